// Round 2
// baseline (316.346 us; speedup 1.0000x reference)
//
#include <hip/hip_runtime.h>
#include <hip/hip_bf16.h>

// Problem constants
#define NG   8
#define ND   16
#define NL   1024
#define NB   16
#define NE   8
#define NOUT 64
#define NKS  3
#define NK   4
#define NLP  1022   // L - KS + 1

// Output layout (flat concat of reference return tuple)
#define OUT_LOSS  (NB*NG*NOUT*NLP)   // 8372224
#define OUT_GATES (OUT_LOSS + 1)     // 8372225

// tanh via exp2 (v_exp_f32 + v_rcp_f32): tanh(x) = 1 - 2/(1+2^(2*log2(e)*x))
// Correct limits: x->+inf => 1, x->-inf => -1. ~2 ulp accuracy.
__device__ __forceinline__ float tanh_fast(float x) {
    float e = exp2f(x * 2.885390081777927f);   // 2*log2(e)
    return 1.0f - 2.0f / (e + 1.0f);
}

// ---------------------------------------------------------------------------
// Kernel 1: gating (softmax -> top4 -> normalized gates), gates_out, loss.
// One block, 128 threads: thread t -> (g = t>>4, b = t&15).
// ---------------------------------------------------------------------------
__global__ __launch_bounds__(128) void gate_kernel(
    const float* __restrict__ x, const float* __restrict__ wg,
    float* __restrict__ out, float* __restrict__ ws_gates)
{
    const int t = threadIdx.x;          // 0..127
    const int g = t >> 4, b = t & 15;

    // gate_in = x[b, g*16+d, 1018+tt]  (L-6 .. L-2), reshaped (d*5+tt)
    float gi[80];
    const float* xrow = x + (size_t)(b * 128 + g * 16) * 1024 + (1024 - 6);
    #pragma unroll
    for (int d = 0; d < 16; ++d) {
        #pragma unroll
        for (int tt = 0; tt < 5; ++tt) gi[d * 5 + tt] = xrow[d * 1024 + tt];
    }

    // logits = gate_in @ wg[g]   (80 x 8)
    float lg[8];
    #pragma unroll
    for (int e = 0; e < 8; ++e) lg[e] = 0.f;
    const float* wgg = wg + g * 80 * 8;
    #pragma unroll
    for (int j = 0; j < 80; ++j) {
        const float v = gi[j];
        #pragma unroll
        for (int e = 0; e < 8; ++e) lg[e] = fmaf(v, wgg[j * 8 + e], lg[e]);
    }

    // softmax (8)
    float mx = lg[0];
    #pragma unroll
    for (int e = 1; e < 8; ++e) mx = fmaxf(mx, lg[e]);
    float s = 0.f;
    #pragma unroll
    for (int e = 0; e < 8; ++e) { lg[e] = expf(lg[e] - mx); s += lg[e]; }
    const float invsm = 1.f / s;
    #pragma unroll
    for (int e = 0; e < 8; ++e) lg[e] *= invsm;

    // top-4 (strict >, first-index tie-break == jax top_k order), static indexing
    int used = 0;
    float tv[4]; int ti[4];
    #pragma unroll
    for (int k = 0; k < 4; ++k) {
        float bv = -1.f; int be = 0;
        #pragma unroll
        for (int e = 0; e < 8; ++e) {
            if (!((used >> e) & 1) && lg[e] > bv) { bv = lg[e]; be = e; }
        }
        tv[k] = bv; ti[k] = be; used |= (1 << be);
    }
    const float s4 = tv[0] + tv[1] + tv[2] + tv[3];
    const float invs = 1.f / (s4 + 1e-6f);

    float gates[8];
    #pragma unroll
    for (int e = 0; e < 8; ++e) {
        float v = 0.f;
        #pragma unroll
        for (int k = 0; k < 4; ++k) if (ti[k] == e) v = tv[k] * invs;
        gates[e] = v;
        ws_gates[t * 8 + e] = v;
        // gates_out[b, e, g]
        out[OUT_GATES + (b * 8 + e) * 8 + g] = v;
    }

    // ---- loss: per group, cv^2(importance) + cv^2(load), ddof=1 over E=8 ----
    __shared__ float glds[128][8];
    #pragma unroll
    for (int e = 0; e < 8; ++e) glds[t][e] = gates[e];
    __syncthreads();

    __shared__ float impa[64], loda[64];
    if (t < 64) {
        const int gg = t >> 3, e = t & 7;
        float si = 0.f, sl = 0.f;
        for (int bb = 0; bb < 16; ++bb) {
            const float v = glds[gg * 16 + bb][e];
            si += v;
            sl += (v > 0.f) ? 1.f : 0.f;
        }
        impa[t] = si; loda[t] = sl;
    }
    __syncthreads();

    __shared__ float lossg[8];
    if (t < 8) {
        float m1 = 0.f, m2 = 0.f;
        #pragma unroll
        for (int e = 0; e < 8; ++e) { m1 += impa[t * 8 + e]; m2 += loda[t * 8 + e]; }
        m1 *= 0.125f; m2 *= 0.125f;
        float v1 = 0.f, v2 = 0.f;
        #pragma unroll
        for (int e = 0; e < 8; ++e) {
            const float d1 = impa[t * 8 + e] - m1, d2 = loda[t * 8 + e] - m2;
            v1 += d1 * d1; v2 += d2 * d2;
        }
        v1 *= (1.f / 7.f); v2 *= (1.f / 7.f);
        lossg[t] = v1 / (m1 * m1 + 1e-10f) + v2 / (m2 * m2 + 1e-10f);
    }
    __syncthreads();
    if (t == 0) {
        float tot = 0.f;
        #pragma unroll
        for (int gg = 0; gg < 8; ++gg) tot += lossg[gg];
        out[OUT_LOSS] = 0.01f * tot;
    }
}

// ---------------------------------------------------------------------------
// Kernel 2: fold gates into conv2 weights: W_eff[g,b,o,i] = sum_e g_e * c2w[g,o*8+e,i]
// 128 blocks (one per (g,b)), 256 threads: thread -> (o = t>>2, i-quarter = t&3).
// float4 loads/stores, fully coalesced.
// ---------------------------------------------------------------------------
__global__ __launch_bounds__(256) void weff_kernel(
    const float* __restrict__ gates, const float* __restrict__ c2w,
    const float* __restrict__ c2b,
    float* __restrict__ weff, float* __restrict__ beff)
{
    const int gb = blockIdx.x;           // 0..127
    const int g  = gb >> 4;
    const int t  = threadIdx.x;
    const int o  = t >> 2;               // 0..63
    const int iq = (t & 3) * 16;         // 0,16,32,48

    float gt[8];
    #pragma unroll
    for (int e = 0; e < 8; ++e) gt[e] = gates[gb * 8 + e];

    const float* w2g = c2w + (size_t)g * 512 * 64 + (size_t)o * 8 * 64 + iq;
    float acc[16];
    #pragma unroll
    for (int q = 0; q < 16; ++q) acc[q] = 0.f;
    #pragma unroll
    for (int e = 0; e < 8; ++e) {
        const float4* src = (const float4*)(w2g + e * 64);
        #pragma unroll
        for (int q = 0; q < 4; ++q) {
            float4 v = src[q];
            acc[q*4+0] = fmaf(gt[e], v.x, acc[q*4+0]);
            acc[q*4+1] = fmaf(gt[e], v.y, acc[q*4+1]);
            acc[q*4+2] = fmaf(gt[e], v.z, acc[q*4+2]);
            acc[q*4+3] = fmaf(gt[e], v.w, acc[q*4+3]);
        }
    }
    float4* dst = (float4*)(weff + (size_t)gb * 4096 + o * 64 + iq);
    #pragma unroll
    for (int q = 0; q < 4; ++q) {
        float4 v; v.x = acc[q*4+0]; v.y = acc[q*4+1]; v.z = acc[q*4+2]; v.w = acc[q*4+3];
        dst[q] = v;
    }

    // b_eff[o] = sum_e g_e * c2b[g, o*8+e]
    if (t < 64) {
        const float* b2g = c2b + g * 512;
        float a = 0.f;
        #pragma unroll
        for (int e = 0; e < 8; ++e) a = fmaf(gt[e], b2g[t * 8 + e], a);
        beff[gb * 64 + t] = a;
    }
}

// ---------------------------------------------------------------------------
// Kernel 3: fused conv1 -> tanh -> (gate-folded 64x64) -> output.
// Grid: 1024 blocks = (gb, ltile[8 x 128]); 256 threads = 128 cols x 2 o-halves.
// h passes through LDS hT[64][128]: both write (along col) and read (along col)
// are conflict-free. Each thread streams HALF the weights (wave-uniform s_loads)
// and 4 waves/SIMD hide the scalar-load latency.
// ---------------------------------------------------------------------------
__global__ __launch_bounds__(256, 4) void main_kernel(
    const float* __restrict__ x, const float* __restrict__ w1,
    const float* __restrict__ b1, const float* __restrict__ weff,
    const float* __restrict__ beff, float* __restrict__ out)
{
    __shared__ float hT[64][128];

    const int bid  = blockIdx.x;
    const int tile = bid & 7;            // 8 tiles of 128 cols
    const int gb   = bid >> 3;           // 0..127
    const int g    = gb >> 4, b = gb & 15;
    const int t    = threadIdx.x;
    const int col  = t & 127;
    const int half = t >> 7;             // 0/1 -> o in [half*32, half*32+32)
    const int l    = tile * 128 + col;
    const bool live = (l < NLP);
    const int obase = half * 32;

    // ---- phase 1: conv1 + tanh for this column, 32 of 64 channels ----
    if (live) {
        const float* xb = x + (size_t)(b * 128 + g * 16) * 1024 + l;
        float xv[48];
        #pragma unroll
        for (int i = 0; i < 16; ++i) {
            xv[i*3+0] = xb[i * 1024 + 0];
            xv[i*3+1] = xb[i * 1024 + 1];
            xv[i*3+2] = xb[i * 1024 + 2];
        }
        const float* w1g = w1 + (size_t)(g * 64 + obase) * 48;
        const float* b1g = b1 + g * 64 + obase;
        #pragma unroll
        for (int o = 0; o < 32; ++o) {
            float acc = b1g[o];
            const float* wr = w1g + o * 48;
            #pragma unroll
            for (int j = 0; j < 48; ++j) acc = fmaf(wr[j], xv[j], acc);
            hT[obase + o][col] = tanh_fast(acc);
        }
    }
    __syncthreads();
    if (!live) return;

    // ---- phase 2: load full h column, gate-folded 64x64 matvec (half) ----
    float h[64];
    #pragma unroll
    for (int i = 0; i < 64; ++i) h[i] = hT[i][col];

    const float* wef = weff + (size_t)gb * 4096 + (size_t)obase * 64;
    const float* bef = beff + gb * 64 + obase;
    float* ob = out + ((size_t)((b * 8 + g) * 64 + obase)) * NLP + l;
    #pragma unroll
    for (int o = 0; o < 32; ++o) {
        float acc = bef[o];
        const float* wr = wef + o * 64;
        #pragma unroll
        for (int i = 0; i < 64; ++i) acc = fmaf(wr[i], h[i], acc);
        ob[(size_t)o * NLP] = acc;
    }
}

// ---------------------------------------------------------------------------
extern "C" void kernel_launch(void* const* d_in, const int* in_sizes, int n_in,
                              void* d_out, int out_size, void* d_ws, size_t ws_size,
                              hipStream_t stream) {
    const float* x   = (const float*)d_in[0];
    const float* wg  = (const float*)d_in[1];
    const float* c1w = (const float*)d_in[2];
    const float* c1b = (const float*)d_in[3];
    const float* c2w = (const float*)d_in[4];
    const float* c2b = (const float*)d_in[5];
    float* out = (float*)d_out;

    float* ws       = (float*)d_ws;
    float* ws_gates = ws;                  // 128*8      = 1024 floats
    float* beff     = ws + 1024;           // 128*64     = 8192 floats
    float* weff     = ws + 1024 + 8192;    // 128*64*64  = 524288 floats
    // total ws: ~2.1 MB

    gate_kernel<<<1, 128, 0, stream>>>(x, wg, out, ws_gates);
    weff_kernel<<<128, 256, 0, stream>>>(ws_gates, c2w, c2b, weff, beff);
    main_kernel<<<1024, 256, 0, stream>>>(x, c1w, c1b, weff, beff, out);
}

// Round 3
// 143.641 us; speedup vs baseline: 2.2023x; 2.2023x over previous
//
#include <hip/hip_runtime.h>
#include <hip/hip_bf16.h>

// Problem constants
#define NG   8
#define ND   16
#define NL   1024
#define NB   16
#define NE   8
#define NOUT 64
#define NKS  3
#define NK   4
#define NLP  1022   // L - KS + 1

// Output layout (flat concat of reference return tuple)
#define OUT_LOSS  (NB*NG*NOUT*NLP)   // 8372224
#define OUT_GATES (OUT_LOSS + 1)     // 8372225

// tanh via exp2: tanh(x) = 1 - 2/(1+2^(2*log2(e)*x)). Correct +-inf limits.
__device__ __forceinline__ float tanh_fast(float x) {
    float e = exp2f(x * 2.885390081777927f);   // 2*log2(e)
    return 1.0f - 2.0f / (e + 1.0f);
}

// Gating math for one (g,b): softmax(80x8 matvec) -> top4 -> renorm.
// Deterministic fp32 sequence, used identically by weff blocks (uniform g,b)
// and the gate-output block (per-thread g,b).
__device__ __forceinline__ void compute_gates_f(
    const float* __restrict__ x, const float* __restrict__ wg,
    int g, int b, float gates[8])
{
    float gi[80];
    const float* xrow = x + (size_t)(b * 128 + g * 16) * 1024 + (1024 - 6);
    #pragma unroll
    for (int d = 0; d < 16; ++d) {
        #pragma unroll
        for (int tt = 0; tt < 5; ++tt) gi[d * 5 + tt] = xrow[d * 1024 + tt];
    }

    float lg[8];
    #pragma unroll
    for (int e = 0; e < 8; ++e) lg[e] = 0.f;
    const float* wgg = wg + g * 640;
    #pragma unroll
    for (int j = 0; j < 80; ++j) {
        const float v = gi[j];
        #pragma unroll
        for (int e = 0; e < 8; ++e) lg[e] = fmaf(v, wgg[j * 8 + e], lg[e]);
    }

    float mx = lg[0];
    #pragma unroll
    for (int e = 1; e < 8; ++e) mx = fmaxf(mx, lg[e]);
    float s = 0.f;
    #pragma unroll
    for (int e = 0; e < 8; ++e) { lg[e] = expf(lg[e] - mx); s += lg[e]; }
    const float invsm = 1.f / s;
    #pragma unroll
    for (int e = 0; e < 8; ++e) lg[e] *= invsm;

    // top-4, strict >, first-index tie-break (jax top_k order)
    int used = 0;
    float tv[4]; int ti[4];
    #pragma unroll
    for (int k = 0; k < 4; ++k) {
        float bv = -1.f; int be = 0;
        #pragma unroll
        for (int e = 0; e < 8; ++e) {
            if (!((used >> e) & 1) && lg[e] > bv) { bv = lg[e]; be = e; }
        }
        tv[k] = bv; ti[k] = be; used |= (1 << be);
    }
    const float s4 = tv[0] + tv[1] + tv[2] + tv[3];
    const float invs = 1.f / (s4 + 1e-6f);
    #pragma unroll
    for (int e = 0; e < 8; ++e) {
        float v = 0.f;
        #pragma unroll
        for (int k = 0; k < 4; ++k) if (ti[k] == e) v = tv[k] * invs;
        gates[e] = v;
    }
}

// ---------------------------------------------------------------------------
// Prep kernel, 137 blocks x 256 threads; all block roles mutually independent.
//   blocks 0..127 : W_eff[gb] = sum_e gate_e * c2w[g,o*8+e,:], b_eff (gates
//                   recomputed locally, wave-uniform -> scalar path)
//   blocks 128..135: repack conv1 weights w1r[g][j=d*3+tap][o] = c1w[g][o][j]
//   block 136     : gates_out + load-balancing loss -> out
// ---------------------------------------------------------------------------
__global__ __launch_bounds__(256) void prep_kernel(
    const float* __restrict__ x,   const float* __restrict__ wg,
    const float* __restrict__ c1w, const float* __restrict__ c2w,
    const float* __restrict__ c2b,
    float* __restrict__ out, float* __restrict__ weff,
    float* __restrict__ beff, float* __restrict__ w1r)
{
    const int bid = blockIdx.x;
    const int t   = threadIdx.x;

    __shared__ float glds[128][8];
    __shared__ float impa[64], loda[64];
    __shared__ float lossg[8];

    if (bid < 128) {
        // ---- W_eff / b_eff for gb = bid ----
        const int gb = bid, g = gb >> 4, b = gb & 15;
        float gt[8];
        compute_gates_f(x, wg, g, b, gt);   // uniform across block

        const int o  = t >> 2;               // 0..63
        const int iq = (t & 3) * 16;         // 0,16,32,48
        const float* w2g = c2w + (size_t)g * 512 * 64 + (size_t)o * 8 * 64 + iq;
        float acc[16];
        #pragma unroll
        for (int q = 0; q < 16; ++q) acc[q] = 0.f;
        #pragma unroll
        for (int e = 0; e < 8; ++e) {
            const float4* src = (const float4*)(w2g + e * 64);
            #pragma unroll
            for (int q = 0; q < 4; ++q) {
                float4 v = src[q];
                acc[q*4+0] = fmaf(gt[e], v.x, acc[q*4+0]);
                acc[q*4+1] = fmaf(gt[e], v.y, acc[q*4+1]);
                acc[q*4+2] = fmaf(gt[e], v.z, acc[q*4+2]);
                acc[q*4+3] = fmaf(gt[e], v.w, acc[q*4+3]);
            }
        }
        float4* dst = (float4*)(weff + (size_t)gb * 4096 + o * 64 + iq);
        #pragma unroll
        for (int q = 0; q < 4; ++q) {
            float4 v; v.x = acc[q*4+0]; v.y = acc[q*4+1];
                      v.z = acc[q*4+2]; v.w = acc[q*4+3];
            dst[q] = v;
        }
        if (t < 64) {
            const float* b2g = c2b + g * 512;
            float a = 0.f;
            #pragma unroll
            for (int e = 0; e < 8; ++e) a = fmaf(gt[e], b2g[t * 8 + e], a);
            beff[gb * 64 + t] = a;
        }
    } else if (bid < 136) {
        // ---- conv1 weight repack for g = bid-128 ----
        const int g = bid - 128;
        for (int idx = t; idx < 48 * 64; idx += 256) {
            const int j = idx >> 6, o = idx & 63;
            w1r[(size_t)(g * 48 + j) * 64 + o] = c1w[(size_t)g * 3072 + o * 48 + j];
        }
    } else {
        // ---- gates_out + loss (threads 0..127 active for compute) ----
        float gates[8];
        const int g = t >> 4, b = t & 15;
        if (t < 128) {
            compute_gates_f(x, wg, g, b, gates);
            #pragma unroll
            for (int e = 0; e < 8; ++e) {
                glds[t][e] = gates[e];
                out[OUT_GATES + (b * 8 + e) * 8 + g] = gates[e];
            }
        }
        __syncthreads();
        if (t < 64) {
            const int gg = t >> 3, e = t & 7;
            float si = 0.f, sl = 0.f;
            for (int bb = 0; bb < 16; ++bb) {
                const float v = glds[gg * 16 + bb][e];
                si += v;
                sl += (v > 0.f) ? 1.f : 0.f;
            }
            impa[t] = si; loda[t] = sl;
        }
        __syncthreads();
        if (t < 8) {
            float m1 = 0.f, m2 = 0.f;
            #pragma unroll
            for (int e = 0; e < 8; ++e) { m1 += impa[t * 8 + e]; m2 += loda[t * 8 + e]; }
            m1 *= 0.125f; m2 *= 0.125f;
            float v1 = 0.f, v2 = 0.f;
            #pragma unroll
            for (int e = 0; e < 8; ++e) {
                const float d1 = impa[t * 8 + e] - m1, d2 = loda[t * 8 + e] - m2;
                v1 += d1 * d1; v2 += d2 * d2;
            }
            v1 *= (1.f / 7.f); v2 *= (1.f / 7.f);
            lossg[t] = v1 / (m1 * m1 + 1e-10f) + v2 / (m2 * m2 + 1e-10f);
        }
        __syncthreads();
        if (t == 0) {
            float tot = 0.f;
            #pragma unroll
            for (int gg = 0; gg < 8; ++gg) tot += lossg[gg];
            out[OUT_LOSS] = 0.01f * tot;
        }
    }
}

// ---------------------------------------------------------------------------
// Main kernel: conv1 -> tanh -> LDS handoff -> gate-folded 64x64 -> out.
// Grid 2048 = gb(128) x ltile(16 x 64 cols). Block 256 = 64 cols x 4 o-quarters.
// Wave (64 lanes) == one o-quarter -> obase is wave-uniform; readfirstlane
// makes that provable so ALL weight streams are s_load (no VGPR cost).
// Register discipline: phase1 acc[16]+3 taps; phase2 a[16]+hh[32] (two h
// halves) -> peak ~60 VGPR, no scratch (round-2 lesson).
// ---------------------------------------------------------------------------
__global__ __launch_bounds__(256, 6) void main_kernel(
    const float* __restrict__ x,    const float* __restrict__ w1r,
    const float* __restrict__ b1,   const float* __restrict__ weff,
    const float* __restrict__ beff, float* __restrict__ out)
{
    __shared__ float hT[64][64];   // 16 KB; [o][col], b32 access both ways: conflict-free

    const int bid   = blockIdx.x;
    const int tile  = bid & 15;
    const int gb    = bid >> 4;
    const int g     = gb >> 4, b = gb & 15;
    const int t     = threadIdx.x;
    const int col   = t & 63;
    const int obase = __builtin_amdgcn_readfirstlane((t >> 6) << 4); // wave-uniform
    const int l     = tile * 64 + col;
    const int lc    = (l < NLP) ? l : (NLP - 1);   // clamp tail loads in-bounds

    // ---- phase 1: conv1 (16 of 64 channels) + tanh ----
    float acc[16];
    const float* b1g = b1 + g * 64 + obase;
    #pragma unroll
    for (int o = 0; o < 16; ++o) acc[o] = b1g[o];

    const float* xb  = x + (size_t)(b * 128 + g * 16) * 1024 + lc;
    const float* wrg = w1r + (size_t)(g * 48) * 64 + obase;
    #pragma unroll
    for (int i = 0; i < 16; ++i) {
        const float x0 = xb[i * 1024 + 0];
        const float x1 = xb[i * 1024 + 1];
        const float x2 = xb[i * 1024 + 2];
        const float* wr = wrg + i * 192;   // 3 rows of 64 (we use 16 at obase)
        #pragma unroll
        for (int o = 0; o < 16; ++o) acc[o] = fmaf(wr[o],       x0, acc[o]);
        #pragma unroll
        for (int o = 0; o < 16; ++o) acc[o] = fmaf(wr[64 + o],  x1, acc[o]);
        #pragma unroll
        for (int o = 0; o < 16; ++o) acc[o] = fmaf(wr[128 + o], x2, acc[o]);
    }
    #pragma unroll
    for (int o = 0; o < 16; ++o) hT[obase + o][col] = tanh_fast(acc[o]);

    __syncthreads();

    // ---- phase 2: gate-folded 64x64 matvec, h consumed in two 32-halves ----
    float a[16];
    const float* bef = beff + gb * 64 + obase;
    #pragma unroll
    for (int o = 0; o < 16; ++o) a[o] = bef[o];

    const float* wef = weff + (size_t)gb * 4096 + (size_t)obase * 64;
    {
        float hh[32];
        #pragma unroll
        for (int i = 0; i < 32; ++i) hh[i] = hT[i][col];
        #pragma unroll
        for (int o = 0; o < 16; ++o) {
            const float* wr = wef + o * 64;
            #pragma unroll
            for (int i = 0; i < 32; ++i) a[o] = fmaf(wr[i], hh[i], a[o]);
        }
    }
    {
        float hh[32];
        #pragma unroll
        for (int i = 0; i < 32; ++i) hh[i] = hT[32 + i][col];
        #pragma unroll
        for (int o = 0; o < 16; ++o) {
            const float* wr = wef + o * 64 + 32;
            #pragma unroll
            for (int i = 0; i < 32; ++i) a[o] = fmaf(wr[i], hh[i], a[o]);
        }
    }

    if (l < NLP) {
        float* ob = out + ((size_t)((b * 8 + g) * 64 + obase)) * NLP + l;
        #pragma unroll
        for (int o = 0; o < 16; ++o) ob[(size_t)o * NLP] = a[o];
    }
}

// ---------------------------------------------------------------------------
extern "C" void kernel_launch(void* const* d_in, const int* in_sizes, int n_in,
                              void* d_out, int out_size, void* d_ws, size_t ws_size,
                              hipStream_t stream) {
    const float* x   = (const float*)d_in[0];
    const float* wg  = (const float*)d_in[1];
    const float* c1w = (const float*)d_in[2];
    const float* c1b = (const float*)d_in[3];
    const float* c2w = (const float*)d_in[4];
    const float* c2b = (const float*)d_in[5];
    float* out = (float*)d_out;

    float* ws   = (float*)d_ws;
    float* beff = ws;                        // 128*64      = 8192 floats
    float* weff = ws + 8192;                 // 128*64*64   = 524288 floats
    float* w1r  = ws + 8192 + 524288;        // 8*48*64     = 24576 floats
    // total ws: ~2.23 MB

    prep_kernel<<<137, 256, 0, stream>>>(x, wg, c1w, c2w, c2b, out, weff, beff, w1r);
    main_kernel<<<2048, 256, 0, stream>>>(x, w1r, c1b, weff, beff, out);
}

// Round 4
// 132.069 us; speedup vs baseline: 2.3953x; 1.0876x over previous
//
#include <hip/hip_runtime.h>
#include <hip/hip_bf16.h>

// Problem constants
#define NG   8
#define ND   16
#define NL   1024
#define NB   16
#define NE   8
#define NOUT 64
#define NKS  3
#define NK   4
#define NLP  1022   // L - KS + 1

// Output layout (flat concat of reference return tuple)
#define OUT_LOSS  (NB*NG*NOUT*NLP)   // 8372224
#define OUT_GATES (OUT_LOSS + 1)     // 8372225

// tanh via exp2: tanh(x) = 1 - 2/(1+2^(2*log2(e)*x)). Correct +-inf limits.
__device__ __forceinline__ float tanh_fast(float x) {
    float e = exp2f(x * 2.885390081777927f);   // 2*log2(e)
    return 1.0f - 2.0f / (e + 1.0f);
}

// Gating math for one (g,b): softmax(80x8 matvec) -> top4 -> renorm.
__device__ __forceinline__ void compute_gates_f(
    const float* __restrict__ x, const float* __restrict__ wg,
    int g, int b, float gates[8])
{
    float gi[80];
    const float* xrow = x + (size_t)(b * 128 + g * 16) * 1024 + (1024 - 6);
    #pragma unroll
    for (int d = 0; d < 16; ++d) {
        #pragma unroll
        for (int tt = 0; tt < 5; ++tt) gi[d * 5 + tt] = xrow[d * 1024 + tt];
    }

    float lg[8];
    #pragma unroll
    for (int e = 0; e < 8; ++e) lg[e] = 0.f;
    const float* wgg = wg + g * 640;
    #pragma unroll
    for (int j = 0; j < 80; ++j) {
        const float v = gi[j];
        #pragma unroll
        for (int e = 0; e < 8; ++e) lg[e] = fmaf(v, wgg[j * 8 + e], lg[e]);
    }

    float mx = lg[0];
    #pragma unroll
    for (int e = 1; e < 8; ++e) mx = fmaxf(mx, lg[e]);
    float s = 0.f;
    #pragma unroll
    for (int e = 0; e < 8; ++e) { lg[e] = expf(lg[e] - mx); s += lg[e]; }
    const float invsm = 1.f / s;
    #pragma unroll
    for (int e = 0; e < 8; ++e) lg[e] *= invsm;

    // top-4, strict >, first-index tie-break (jax top_k order)
    int used = 0;
    float tv[4]; int ti[4];
    #pragma unroll
    for (int k = 0; k < 4; ++k) {
        float bv = -1.f; int be = 0;
        #pragma unroll
        for (int e = 0; e < 8; ++e) {
            if (!((used >> e) & 1) && lg[e] > bv) { bv = lg[e]; be = e; }
        }
        tv[k] = bv; ti[k] = be; used |= (1 << be);
    }
    const float s4 = tv[0] + tv[1] + tv[2] + tv[3];
    const float invs = 1.f / (s4 + 1e-6f);
    #pragma unroll
    for (int e = 0; e < 8; ++e) {
        float v = 0.f;
        #pragma unroll
        for (int k = 0; k < 4; ++k) if (ti[k] == e) v = tv[k] * invs;
        gates[e] = v;
    }
}

// ---------------------------------------------------------------------------
// Prep kernel, 137 blocks x 256 threads (unchanged from round 3 - passed,
// est. ~4 us):
//   blocks 0..127  : W_eff[gb], b_eff[gb]  (gates recomputed, scalar path)
//   blocks 128..135: repack conv1 weights w1r[g][j=d*3+tap][o]
//   block 136      : gates_out + load-balancing loss
// ---------------------------------------------------------------------------
__global__ __launch_bounds__(256) void prep_kernel(
    const float* __restrict__ x,   const float* __restrict__ wg,
    const float* __restrict__ c1w, const float* __restrict__ c2w,
    const float* __restrict__ c2b,
    float* __restrict__ out, float* __restrict__ weff,
    float* __restrict__ beff, float* __restrict__ w1r)
{
    const int bid = blockIdx.x;
    const int t   = threadIdx.x;

    __shared__ float glds[128][8];
    __shared__ float impa[64], loda[64];
    __shared__ float lossg[8];

    if (bid < 128) {
        const int gb = bid, g = gb >> 4, b = gb & 15;
        float gt[8];
        compute_gates_f(x, wg, g, b, gt);   // uniform across block

        const int o  = t >> 2;               // 0..63
        const int iq = (t & 3) * 16;         // 0,16,32,48
        const float* w2g = c2w + (size_t)g * 512 * 64 + (size_t)o * 8 * 64 + iq;
        float acc[16];
        #pragma unroll
        for (int q = 0; q < 16; ++q) acc[q] = 0.f;
        #pragma unroll
        for (int e = 0; e < 8; ++e) {
            const float4* src = (const float4*)(w2g + e * 64);
            #pragma unroll
            for (int q = 0; q < 4; ++q) {
                float4 v = src[q];
                acc[q*4+0] = fmaf(gt[e], v.x, acc[q*4+0]);
                acc[q*4+1] = fmaf(gt[e], v.y, acc[q*4+1]);
                acc[q*4+2] = fmaf(gt[e], v.z, acc[q*4+2]);
                acc[q*4+3] = fmaf(gt[e], v.w, acc[q*4+3]);
            }
        }
        float4* dst = (float4*)(weff + (size_t)gb * 4096 + o * 64 + iq);
        #pragma unroll
        for (int q = 0; q < 4; ++q) {
            float4 v; v.x = acc[q*4+0]; v.y = acc[q*4+1];
                      v.z = acc[q*4+2]; v.w = acc[q*4+3];
            dst[q] = v;
        }
        if (t < 64) {
            const float* b2g = c2b + g * 512;
            float a = 0.f;
            #pragma unroll
            for (int e = 0; e < 8; ++e) a = fmaf(gt[e], b2g[t * 8 + e], a);
            beff[gb * 64 + t] = a;
        }
    } else if (bid < 136) {
        const int g = bid - 128;
        for (int idx = t; idx < 48 * 64; idx += 256) {
            const int j = idx >> 6, o = idx & 63;
            w1r[(size_t)(g * 48 + j) * 64 + o] = c1w[(size_t)g * 3072 + o * 48 + j];
        }
    } else {
        float gates[8];
        const int g = t >> 4, b = t & 15;
        if (t < 128) {
            compute_gates_f(x, wg, g, b, gates);
            #pragma unroll
            for (int e = 0; e < 8; ++e) {
                glds[t][e] = gates[e];
                out[OUT_GATES + (b * 8 + e) * 8 + g] = gates[e];
            }
        }
        __syncthreads();
        if (t < 64) {
            const int gg = t >> 3, e = t & 7;
            float si = 0.f, sl = 0.f;
            for (int bb = 0; bb < 16; ++bb) {
                const float v = glds[gg * 16 + bb][e];
                si += v;
                sl += (v > 0.f) ? 1.f : 0.f;
            }
            impa[t] = si; loda[t] = sl;
        }
        __syncthreads();
        if (t < 8) {
            float m1 = 0.f, m2 = 0.f;
            #pragma unroll
            for (int e = 0; e < 8; ++e) { m1 += impa[t * 8 + e]; m2 += loda[t * 8 + e]; }
            m1 *= 0.125f; m2 *= 0.125f;
            float v1 = 0.f, v2 = 0.f;
            #pragma unroll
            for (int e = 0; e < 8; ++e) {
                const float d1 = impa[t * 8 + e] - m1, d2 = loda[t * 8 + e] - m2;
                v1 += d1 * d1; v2 += d2 * d2;
            }
            v1 *= (1.f / 7.f); v2 *= (1.f / 7.f);
            lossg[t] = v1 / (m1 * m1 + 1e-10f) + v2 / (m2 * m2 + 1e-10f);
        }
        __syncthreads();
        if (t == 0) {
            float tot = 0.f;
            #pragma unroll
            for (int gg = 0; gg < 8; ++gg) tot += lossg[gg];
            out[OUT_LOSS] = 0.01f * tot;
        }
    }
}

// ---------------------------------------------------------------------------
// Main kernel: conv1 -> tanh -> LDS handoff -> gate-folded 64x64 -> out.
// Grid 1024 = gb(128) x ltile(8 x 128 cols). Block 256 = 4 waves.
// Each lane owns TWO ADJACENT columns (c0=2*lane, c1=c0+1); each wave owns an
// o-quarter (16 channels, wave-uniform via readfirstlane -> pure s_load weight
// streams). 2 cols/lane doubles fma work per scalar weight batch (~128 cyc of
// compute per s_load_dwordx16), and makes x loads float2-coalesced, hT traffic
// ds_write_b64/ds_read_b64 (contiguous, full-BW), stores float2.
// Register discipline: phase1 acc[2][16]+4 taps; phase2 a[2][16]+hh[16]float2
// chunks -> peak ~80 VGPR, no scratch.
// ---------------------------------------------------------------------------
__global__ __launch_bounds__(256, 4) void main_kernel(
    const float* __restrict__ x,    const float* __restrict__ w1r,
    const float* __restrict__ b1,   const float* __restrict__ weff,
    const float* __restrict__ beff, float* __restrict__ out)
{
    __shared__ float hT[64][128];   // 32 KB; [o][col]

    const int bid   = blockIdx.x;
    const int tile  = bid & 7;             // 8 tiles of 128 cols
    const int gb    = bid >> 3;            // 0..127
    const int g     = gb >> 4, b = gb & 15;
    const int t     = threadIdx.x;
    const int lane  = t & 63;
    const int obase = __builtin_amdgcn_readfirstlane((t >> 6) << 4); // wave-uniform
    const int c0    = lane * 2;            // local col pair (c0, c0+1)
    const int l0    = tile * 128 + c0;     // global col of c0
    const int lc    = (l0 <= NLP - 2) ? l0 : (NLP - 2);  // clamp (NLP even)

    // ---- phase 1: conv1 (16 of 64 channels) + tanh, 2 cols ----
    float a0[16], a1[16];
    const float* b1g = b1 + g * 64 + obase;
    #pragma unroll
    for (int o = 0; o < 16; ++o) { a0[o] = b1g[o]; a1[o] = a0[o]; }

    const float* xb  = x + (size_t)(b * 128 + g * 16) * 1024 + lc;
    const float* wrg = w1r + (size_t)(g * 48) * 64 + obase;
    #pragma unroll
    for (int i = 0; i < 16; ++i) {
        // need x[lc..lc+3]: two 8B-aligned float2 loads
        const float2 xa = *(const float2*)(xb + i * 1024);      // x0, x1
        const float2 xc = *(const float2*)(xb + i * 1024 + 2);  // x2, x3
        const float* wr = wrg + i * 192;   // 3 tap-rows of 64
        #pragma unroll
        for (int o = 0; o < 16; ++o) {
            const float w0 = wr[o], w1 = wr[64 + o], w2 = wr[128 + o];
            a0[o] = fmaf(w0, xa.x, a0[o]);
            a0[o] = fmaf(w1, xa.y, a0[o]);
            a0[o] = fmaf(w2, xc.x, a0[o]);
            a1[o] = fmaf(w0, xa.y, a1[o]);
            a1[o] = fmaf(w1, xc.x, a1[o]);
            a1[o] = fmaf(w2, xc.y, a1[o]);
        }
    }
    #pragma unroll
    for (int o = 0; o < 16; ++o) {
        float2 hv; hv.x = tanh_fast(a0[o]); hv.y = tanh_fast(a1[o]);
        *(float2*)&hT[obase + o][c0] = hv;
    }

    __syncthreads();

    // ---- phase 2: gate-folded 64x64 matvec, h consumed in 16-row chunks ----
    const float* bef = beff + gb * 64 + obase;
    #pragma unroll
    for (int o = 0; o < 16; ++o) { a0[o] = bef[o]; a1[o] = a0[o]; }

    const float* wef = weff + (size_t)gb * 4096 + (size_t)obase * 64;
    #pragma unroll
    for (int c = 0; c < 4; ++c) {
        float2 hh[16];
        #pragma unroll
        for (int i = 0; i < 16; ++i) hh[i] = *(const float2*)&hT[c * 16 + i][c0];
        #pragma unroll
        for (int o = 0; o < 16; ++o) {
            const float* wr = wef + o * 64 + c * 16;
            #pragma unroll
            for (int i = 0; i < 16; ++i) {
                a0[o] = fmaf(wr[i], hh[i].x, a0[o]);
                a1[o] = fmaf(wr[i], hh[i].y, a1[o]);
            }
        }
    }

    if (l0 <= NLP - 2) {
        float* ob = out + ((size_t)((b * 8 + g) * 64 + obase)) * NLP + l0;
        #pragma unroll
        for (int o = 0; o < 16; ++o) {
            float2 v; v.x = a0[o]; v.y = a1[o];
            *(float2*)(ob + (size_t)o * NLP) = v;
        }
    }
}

// ---------------------------------------------------------------------------
extern "C" void kernel_launch(void* const* d_in, const int* in_sizes, int n_in,
                              void* d_out, int out_size, void* d_ws, size_t ws_size,
                              hipStream_t stream) {
    const float* x   = (const float*)d_in[0];
    const float* wg  = (const float*)d_in[1];
    const float* c1w = (const float*)d_in[2];
    const float* c1b = (const float*)d_in[3];
    const float* c2w = (const float*)d_in[4];
    const float* c2b = (const float*)d_in[5];
    float* out = (float*)d_out;

    float* ws   = (float*)d_ws;
    float* beff = ws;                        // 128*64      = 8192 floats
    float* weff = ws + 8192;                 // 128*64*64   = 524288 floats
    float* w1r  = ws + 8192 + 524288;        // 8*48*64     = 24576 floats
    // total ws: ~2.23 MB

    prep_kernel<<<137, 256, 0, stream>>>(x, wg, c1w, c2w, c2b, out, weff, beff, w1r);
    main_kernel<<<1024, 256, 0, stream>>>(x, w1r, c1b, weff, beff, out);
}

// Round 5
// 125.694 us; speedup vs baseline: 2.5168x; 1.0507x over previous
//
#include <hip/hip_runtime.h>
#include <hip/hip_bf16.h>

// Problem constants
#define NG   8
#define ND   16
#define NL   1024
#define NB   16
#define NE   8
#define NOUT 64
#define NKS  3
#define NK   4
#define NLP  1022   // L - KS + 1

// Output layout (flat concat of reference return tuple)
#define OUT_LOSS  (NB*NG*NOUT*NLP)   // 8372224
#define OUT_GATES (OUT_LOSS + 1)     // 8372225

// tanh via exp2: tanh(x) = 1 - 2/(1+2^(2*log2(e)*x)). Correct +-inf limits.
__device__ __forceinline__ float tanh_fast(float x) {
    float e = exp2f(x * 2.885390081777927f);   // 2*log2(e)
    return 1.0f - 2.0f / (e + 1.0f);
}

// Gating math for one (g,b): softmax(80x8 matvec) -> top4 -> renorm.
__device__ __forceinline__ void compute_gates_f(
    const float* __restrict__ x, const float* __restrict__ wg,
    int g, int b, float gates[8])
{
    float gi[80];
    const float* xrow = x + (size_t)(b * 128 + g * 16) * 1024 + (1024 - 6);
    #pragma unroll
    for (int d = 0; d < 16; ++d) {
        #pragma unroll
        for (int tt = 0; tt < 5; ++tt) gi[d * 5 + tt] = xrow[d * 1024 + tt];
    }

    float lg[8];
    #pragma unroll
    for (int e = 0; e < 8; ++e) lg[e] = 0.f;
    const float* wgg = wg + g * 640;
    #pragma unroll
    for (int j = 0; j < 80; ++j) {
        const float v = gi[j];
        #pragma unroll
        for (int e = 0; e < 8; ++e) lg[e] = fmaf(v, wgg[j * 8 + e], lg[e]);
    }

    float mx = lg[0];
    #pragma unroll
    for (int e = 1; e < 8; ++e) mx = fmaxf(mx, lg[e]);
    float s = 0.f;
    #pragma unroll
    for (int e = 0; e < 8; ++e) { lg[e] = expf(lg[e] - mx); s += lg[e]; }
    const float invsm = 1.f / s;
    #pragma unroll
    for (int e = 0; e < 8; ++e) lg[e] *= invsm;

    // top-4, strict >, first-index tie-break (jax top_k order)
    int used = 0;
    float tv[4]; int ti[4];
    #pragma unroll
    for (int k = 0; k < 4; ++k) {
        float bv = -1.f; int be = 0;
        #pragma unroll
        for (int e = 0; e < 8; ++e) {
            if (!((used >> e) & 1) && lg[e] > bv) { bv = lg[e]; be = e; }
        }
        tv[k] = bv; ti[k] = be; used |= (1 << be);
    }
    const float s4 = tv[0] + tv[1] + tv[2] + tv[3];
    const float invs = 1.f / (s4 + 1e-6f);
    #pragma unroll
    for (int e = 0; e < 8; ++e) {
        float v = 0.f;
        #pragma unroll
        for (int k = 0; k < 4; ++k) if (ti[k] == e) v = tv[k] * invs;
        gates[e] = v;
    }
}

// ---------------------------------------------------------------------------
// Prep kernel, 137 blocks x 256 threads (unchanged from rounds 3/4 - passed):
//   blocks 0..127  : W_eff[gb], b_eff[gb]  (gates recomputed, scalar path)
//   blocks 128..135: repack conv1 weights w1r[g][j=d*3+tap][o]
//   block 136      : gates_out + load-balancing loss
// ---------------------------------------------------------------------------
__global__ __launch_bounds__(256) void prep_kernel(
    const float* __restrict__ x,   const float* __restrict__ wg,
    const float* __restrict__ c1w, const float* __restrict__ c2w,
    const float* __restrict__ c2b,
    float* __restrict__ out, float* __restrict__ weff,
    float* __restrict__ beff, float* __restrict__ w1r)
{
    const int bid = blockIdx.x;
    const int t   = threadIdx.x;

    __shared__ float glds[128][8];
    __shared__ float impa[64], loda[64];
    __shared__ float lossg[8];

    if (bid < 128) {
        const int gb = bid, g = gb >> 4, b = gb & 15;
        float gt[8];
        compute_gates_f(x, wg, g, b, gt);   // uniform across block

        const int o  = t >> 2;               // 0..63
        const int iq = (t & 3) * 16;         // 0,16,32,48
        const float* w2g = c2w + (size_t)g * 512 * 64 + (size_t)o * 8 * 64 + iq;
        float acc[16];
        #pragma unroll
        for (int q = 0; q < 16; ++q) acc[q] = 0.f;
        #pragma unroll
        for (int e = 0; e < 8; ++e) {
            const float4* src = (const float4*)(w2g + e * 64);
            #pragma unroll
            for (int q = 0; q < 4; ++q) {
                float4 v = src[q];
                acc[q*4+0] = fmaf(gt[e], v.x, acc[q*4+0]);
                acc[q*4+1] = fmaf(gt[e], v.y, acc[q*4+1]);
                acc[q*4+2] = fmaf(gt[e], v.z, acc[q*4+2]);
                acc[q*4+3] = fmaf(gt[e], v.w, acc[q*4+3]);
            }
        }
        float4* dst = (float4*)(weff + (size_t)gb * 4096 + o * 64 + iq);
        #pragma unroll
        for (int q = 0; q < 4; ++q) {
            float4 v; v.x = acc[q*4+0]; v.y = acc[q*4+1];
                      v.z = acc[q*4+2]; v.w = acc[q*4+3];
            dst[q] = v;
        }
        if (t < 64) {
            const float* b2g = c2b + g * 512;
            float a = 0.f;
            #pragma unroll
            for (int e = 0; e < 8; ++e) a = fmaf(gt[e], b2g[t * 8 + e], a);
            beff[gb * 64 + t] = a;
        }
    } else if (bid < 136) {
        const int g = bid - 128;
        for (int idx = t; idx < 48 * 64; idx += 256) {
            const int j = idx >> 6, o = idx & 63;
            w1r[(size_t)(g * 48 + j) * 64 + o] = c1w[(size_t)g * 3072 + o * 48 + j];
        }
    } else {
        float gates[8];
        const int g = t >> 4, b = t & 15;
        if (t < 128) {
            compute_gates_f(x, wg, g, b, gates);
            #pragma unroll
            for (int e = 0; e < 8; ++e) {
                glds[t][e] = gates[e];
                out[OUT_GATES + (b * 8 + e) * 8 + g] = gates[e];
            }
        }
        __syncthreads();
        if (t < 64) {
            const int gg = t >> 3, e = t & 7;
            float si = 0.f, sl = 0.f;
            for (int bb = 0; bb < 16; ++bb) {
                const float v = glds[gg * 16 + bb][e];
                si += v;
                sl += (v > 0.f) ? 1.f : 0.f;
            }
            impa[t] = si; loda[t] = sl;
        }
        __syncthreads();
        if (t < 8) {
            float m1 = 0.f, m2 = 0.f;
            #pragma unroll
            for (int e = 0; e < 8; ++e) { m1 += impa[t * 8 + e]; m2 += loda[t * 8 + e]; }
            m1 *= 0.125f; m2 *= 0.125f;
            float v1 = 0.f, v2 = 0.f;
            #pragma unroll
            for (int e = 0; e < 8; ++e) {
                const float d1 = impa[t * 8 + e] - m1, d2 = loda[t * 8 + e] - m2;
                v1 += d1 * d1; v2 += d2 * d2;
            }
            v1 *= (1.f / 7.f); v2 *= (1.f / 7.f);
            lossg[t] = v1 / (m1 * m1 + 1e-10f) + v2 / (m2 * m2 + 1e-10f);
        }
        __syncthreads();
        if (t == 0) {
            float tot = 0.f;
            #pragma unroll
            for (int gg = 0; gg < 8; ++gg) tot += lossg[gg];
            out[OUT_LOSS] = 0.01f * tot;
        }
    }
}

// ---------------------------------------------------------------------------
// Main kernel: conv1 -> tanh -> LDS handoff -> gate-folded 64x64 -> out.
// Grid 1024, block 256 = 4 waves; each wave = one o-quarter (wave-uniform via
// readfirstlane -> all weight streams are s_load); each lane = 2 adjacent cols.
//
// XCD swizzle (T1): bid -> xcd = bid&7, j = bid>>3, gb = 8*(j&15)+xcd,
// tile = j>>4. All 8 tiles of one gb land on the SAME XCD, so its L2 holds
// weff[gb] (16KB) + the gb's x slice (64KB); per-XCD working set = 16 gb
// -> 256KB weff + 1MB x, L2-resident. Kills the round-4 weff HBM re-fetch
// (16MB) and the barrier-correlated HBM-latency s_load chain at phase-2 start.
//
// Latency batching: phase-1 x loads issued in two 8-deep float2 batches ahead
// of use; phase-2 hT reads double-buffered in 16-row chunks. Peak regs ~105
// (< 128 @ 4 waves/SIMD), no scratch.
// ---------------------------------------------------------------------------
__global__ __launch_bounds__(256, 4) void main_kernel(
    const float* __restrict__ x,    const float* __restrict__ w1r,
    const float* __restrict__ b1,   const float* __restrict__ weff,
    const float* __restrict__ beff, float* __restrict__ out)
{
    __shared__ float hT[64][128];   // 32 KB; [o][col]

    const int bid   = blockIdx.x;
    const int xcd   = bid & 7;
    const int j     = bid >> 3;
    const int gb    = ((j & 15) << 3) | xcd;   // same-gb tiles share an XCD
    const int tile  = j >> 4;                  // 0..7
    const int g     = gb >> 4, b = gb & 15;
    const int t     = threadIdx.x;
    const int lane  = t & 63;
    const int obase = __builtin_amdgcn_readfirstlane((t >> 6) << 4); // wave-uniform
    const int c0    = lane * 2;            // local col pair (c0, c0+1)
    const int l0    = tile * 128 + c0;     // global col of c0
    const int lc    = (l0 <= NLP - 2) ? l0 : (NLP - 2);  // clamp (NLP even)

    // ---- phase 1: conv1 (16 of 64 channels) + tanh, 2 cols ----
    float a0[16], a1[16];
    const float* b1g = b1 + g * 64 + obase;
    #pragma unroll
    for (int o = 0; o < 16; ++o) { a0[o] = b1g[o]; a1[o] = a0[o]; }

    const float* xb  = x + (size_t)(b * 128 + g * 16) * 1024 + lc;
    const float* wrg = w1r + (size_t)(g * 48) * 64 + obase;

    // batch-issue x loads for channels 0..7, then 8..15 (16 loads in flight
    // before first use -> one vmcnt group covers the whole batch)
    float2 xaA[8], xcA[8];
    #pragma unroll
    for (int i = 0; i < 8; ++i) {
        xaA[i] = *(const float2*)(xb + i * 1024);      // x0, x1
        xcA[i] = *(const float2*)(xb + i * 1024 + 2);  // x2, x3
    }
    float2 xaB[8], xcB[8];
    #pragma unroll
    for (int i = 0; i < 8; ++i) {
        xaB[i] = *(const float2*)(xb + (8 + i) * 1024);
        xcB[i] = *(const float2*)(xb + (8 + i) * 1024 + 2);
    }

    #pragma unroll
    for (int i = 0; i < 8; ++i) {
        const float* wr = wrg + i * 192;   // 3 tap-rows of 64
        #pragma unroll
        for (int o = 0; o < 16; ++o) {
            const float w0 = wr[o], w1 = wr[64 + o], w2 = wr[128 + o];
            a0[o] = fmaf(w0, xaA[i].x, a0[o]);
            a0[o] = fmaf(w1, xaA[i].y, a0[o]);
            a0[o] = fmaf(w2, xcA[i].x, a0[o]);
            a1[o] = fmaf(w0, xaA[i].y, a1[o]);
            a1[o] = fmaf(w1, xcA[i].x, a1[o]);
            a1[o] = fmaf(w2, xcA[i].y, a1[o]);
        }
    }
    #pragma unroll
    for (int i = 0; i < 8; ++i) {
        const float* wr = wrg + (8 + i) * 192;
        #pragma unroll
        for (int o = 0; o < 16; ++o) {
            const float w0 = wr[o], w1 = wr[64 + o], w2 = wr[128 + o];
            a0[o] = fmaf(w0, xaB[i].x, a0[o]);
            a0[o] = fmaf(w1, xaB[i].y, a0[o]);
            a0[o] = fmaf(w2, xcB[i].x, a0[o]);
            a1[o] = fmaf(w0, xaB[i].y, a1[o]);
            a1[o] = fmaf(w1, xcB[i].x, a1[o]);
            a1[o] = fmaf(w2, xcB[i].y, a1[o]);
        }
    }
    #pragma unroll
    for (int o = 0; o < 16; ++o) {
        float2 hv; hv.x = tanh_fast(a0[o]); hv.y = tanh_fast(a1[o]);
        *(float2*)&hT[obase + o][c0] = hv;
    }

    __syncthreads();

    // ---- phase 2: gate-folded 64x64 matvec, double-buffered 16-row chunks ----
    const float* bef = beff + gb * 64 + obase;
    #pragma unroll
    for (int o = 0; o < 16; ++o) { a0[o] = bef[o]; a1[o] = a0[o]; }

    const float* wef = weff + (size_t)gb * 4096 + (size_t)obase * 64;

    float2 hhA[16], hhB[16];
    #pragma unroll
    for (int i = 0; i < 16; ++i) hhA[i] = *(const float2*)&hT[i][c0];
    #pragma unroll
    for (int i = 0; i < 16; ++i) hhB[i] = *(const float2*)&hT[16 + i][c0];

    // chunk 0 (A), refill A with chunk 2
    #pragma unroll
    for (int o = 0; o < 16; ++o) {
        const float* wr = wef + o * 64;
        #pragma unroll
        for (int i = 0; i < 16; ++i) {
            a0[o] = fmaf(wr[i], hhA[i].x, a0[o]);
            a1[o] = fmaf(wr[i], hhA[i].y, a1[o]);
        }
    }
    #pragma unroll
    for (int i = 0; i < 16; ++i) hhA[i] = *(const float2*)&hT[32 + i][c0];

    // chunk 1 (B), refill B with chunk 3
    #pragma unroll
    for (int o = 0; o < 16; ++o) {
        const float* wr = wef + o * 64 + 16;
        #pragma unroll
        for (int i = 0; i < 16; ++i) {
            a0[o] = fmaf(wr[i], hhB[i].x, a0[o]);
            a1[o] = fmaf(wr[i], hhB[i].y, a1[o]);
        }
    }
    #pragma unroll
    for (int i = 0; i < 16; ++i) hhB[i] = *(const float2*)&hT[48 + i][c0];

    // chunk 2 (A)
    #pragma unroll
    for (int o = 0; o < 16; ++o) {
        const float* wr = wef + o * 64 + 32;
        #pragma unroll
        for (int i = 0; i < 16; ++i) {
            a0[o] = fmaf(wr[i], hhA[i].x, a0[o]);
            a1[o] = fmaf(wr[i], hhA[i].y, a1[o]);
        }
    }
    // chunk 3 (B)
    #pragma unroll
    for (int o = 0; o < 16; ++o) {
        const float* wr = wef + o * 64 + 48;
        #pragma unroll
        for (int i = 0; i < 16; ++i) {
            a0[o] = fmaf(wr[i], hhB[i].x, a0[o]);
            a1[o] = fmaf(wr[i], hhB[i].y, a1[o]);
        }
    }

    if (l0 <= NLP - 2) {
        float* ob = out + ((size_t)((b * 8 + g) * 64 + obase)) * NLP + l0;
        #pragma unroll
        for (int o = 0; o < 16; ++o) {
            float2 v; v.x = a0[o]; v.y = a1[o];
            *(float2*)(ob + (size_t)o * NLP) = v;
        }
    }
}

// ---------------------------------------------------------------------------
extern "C" void kernel_launch(void* const* d_in, const int* in_sizes, int n_in,
                              void* d_out, int out_size, void* d_ws, size_t ws_size,
                              hipStream_t stream) {
    const float* x   = (const float*)d_in[0];
    const float* wg  = (const float*)d_in[1];
    const float* c1w = (const float*)d_in[2];
    const float* c1b = (const float*)d_in[3];
    const float* c2w = (const float*)d_in[4];
    const float* c2b = (const float*)d_in[5];
    float* out = (float*)d_out;

    float* ws   = (float*)d_ws;
    float* beff = ws;                        // 128*64      = 8192 floats
    float* weff = ws + 8192;                 // 128*64*64   = 524288 floats
    float* w1r  = ws + 8192 + 524288;        // 8*48*64     = 24576 floats
    // total ws: ~2.23 MB

    prep_kernel<<<137, 256, 0, stream>>>(x, wg, c1w, c2w, c2b, out, weff, beff, w1r);
    main_kernel<<<1024, 256, 0, stream>>>(x, w1r, c1b, weff, beff, out);
}

// Round 6
// 116.546 us; speedup vs baseline: 2.7143x; 1.0785x over previous
//
#include <hip/hip_runtime.h>
#include <hip/hip_bf16.h>

// Problem constants
#define NG   8
#define ND   16
#define NL   1024
#define NB   16
#define NE   8
#define NOUT 64
#define NKS  3
#define NK   4
#define NLP  1022   // L - KS + 1

// Output layout (flat concat of reference return tuple)
#define OUT_LOSS  (NB*NG*NOUT*NLP)   // 8372224
#define OUT_GATES (OUT_LOSS + 1)     // 8372225

typedef short bf16x8 __attribute__((ext_vector_type(8)));  // 8 bf16 (4 VGPR)
typedef float f32x4  __attribute__((ext_vector_type(4)));  // MFMA acc

// tanh via exp2: tanh(x) = 1 - 2/(1+2^(2*log2(e)*x)). Correct +-inf limits.
__device__ __forceinline__ float tanh_fast(float x) {
    float e = exp2f(x * 2.885390081777927f);   // 2*log2(e)
    return 1.0f - 2.0f / (e + 1.0f);
}

// --- split-bf16 helpers (truncation split: hi = top16 bits, lo = residual) ---
__device__ __forceinline__ unsigned fbits(float a) { return __builtin_bit_cast(unsigned, a); }
__device__ __forceinline__ float resid(float a) {   // a - bf16_trunc(a), exact
    return a - __builtin_bit_cast(float, fbits(a) & 0xFFFF0000u);
}
// pack bf16_trunc(a) into low 16, bf16_trunc(b) into high 16
__device__ __forceinline__ int pack2(float a, float b) {
    return (int)((fbits(a) >> 16) | (fbits(b) & 0xFFFF0000u));
}

// Gating math for one (g,b): softmax(80x8 matvec) -> top4 -> renorm.
__device__ __forceinline__ void compute_gates_f(
    const float* __restrict__ x, const float* __restrict__ wg,
    int g, int b, float gates[8])
{
    float gi[80];
    const float* xrow = x + (size_t)(b * 128 + g * 16) * 1024 + (1024 - 6);
    #pragma unroll
    for (int d = 0; d < 16; ++d) {
        #pragma unroll
        for (int tt = 0; tt < 5; ++tt) gi[d * 5 + tt] = xrow[d * 1024 + tt];
    }
    float lg[8];
    #pragma unroll
    for (int e = 0; e < 8; ++e) lg[e] = 0.f;
    const float* wgg = wg + g * 640;
    #pragma unroll
    for (int j = 0; j < 80; ++j) {
        const float v = gi[j];
        #pragma unroll
        for (int e = 0; e < 8; ++e) lg[e] = fmaf(v, wgg[j * 8 + e], lg[e]);
    }
    float mx = lg[0];
    #pragma unroll
    for (int e = 1; e < 8; ++e) mx = fmaxf(mx, lg[e]);
    float s = 0.f;
    #pragma unroll
    for (int e = 0; e < 8; ++e) { lg[e] = expf(lg[e] - mx); s += lg[e]; }
    const float invsm = 1.f / s;
    #pragma unroll
    for (int e = 0; e < 8; ++e) lg[e] *= invsm;

    int used = 0;
    float tv[4]; int ti[4];
    #pragma unroll
    for (int k = 0; k < 4; ++k) {
        float bv = -1.f; int be = 0;
        #pragma unroll
        for (int e = 0; e < 8; ++e) {
            if (!((used >> e) & 1) && lg[e] > bv) { bv = lg[e]; be = e; }
        }
        tv[k] = bv; ti[k] = be; used |= (1 << be);
    }
    const float s4 = tv[0] + tv[1] + tv[2] + tv[3];
    const float invs = 1.f / (s4 + 1e-6f);
    #pragma unroll
    for (int e = 0; e < 8; ++e) {
        float v = 0.f;
        #pragma unroll
        for (int k = 0; k < 4; ++k) if (ti[k] == e) v = tv[k] * invs;
        gates[e] = v;
    }
}

// ---------------------------------------------------------------------------
// Prep kernel, 137 blocks x 256 threads:
//   blocks 0..127  : weffA[gb] = split-bf16 A-fragments of (sum_e g_e c2w),
//                    beff[gb]  (gates recomputed locally, scalar path)
//   blocks 128..135: repack conv1 weights w1r[g][j=d*3+tap][o]
//   block 136      : gates_out + load-balancing loss
//
// A-fragment k-convention (self-consistent with B, cancels in MFMA):
//   unit(gb,s,mt,ks) at int4 index gb*1024 + s*512 + mt*128 + ks*64 + slot,
//   slot = lgrp*16 + (o&15), element e: i = ks*32 + lgrp*8 + e, o row in mt.
// ---------------------------------------------------------------------------
__global__ __launch_bounds__(256) void prep_kernel(
    const float* __restrict__ x,   const float* __restrict__ wg,
    const float* __restrict__ c1w, const float* __restrict__ c2w,
    const float* __restrict__ c2b,
    float* __restrict__ out, int4* __restrict__ weffA,
    float* __restrict__ beff, float* __restrict__ w1r)
{
    const int bid = blockIdx.x;
    const int t   = threadIdx.x;

    __shared__ float glds[128][8];
    __shared__ float impa[64], loda[64];
    __shared__ float lossg[8];

    if (bid < 128) {
        const int gb = bid, g = gb >> 4, b = gb & 15;
        float gt[8];
        compute_gates_f(x, wg, g, b, gt);   // uniform across block

        const int o  = t >> 2;               // 0..63
        const int iq = (t & 3) * 16;         // 0,16,32,48
        const float* w2g = c2w + (size_t)g * 512 * 64 + (size_t)o * 8 * 64 + iq;
        float acc[16];
        #pragma unroll
        for (int q = 0; q < 16; ++q) acc[q] = 0.f;
        #pragma unroll
        for (int e = 0; e < 8; ++e) {
            const float4* src = (const float4*)(w2g + e * 64);
            #pragma unroll
            for (int q = 0; q < 4; ++q) {
                float4 v = src[q];
                acc[q*4+0] = fmaf(gt[e], v.x, acc[q*4+0]);
                acc[q*4+1] = fmaf(gt[e], v.y, acc[q*4+1]);
                acc[q*4+2] = fmaf(gt[e], v.z, acc[q*4+2]);
                acc[q*4+3] = fmaf(gt[e], v.w, acc[q*4+3]);
            }
        }
        // acc[j] = Weff[o][iq + j]; emit split-bf16 A-fragments
        const int mt  = o >> 4;
        const int ks  = iq >> 5;
        const int lgA = (iq & 31) >> 3;      // 0 or 2
        int4* wdst = weffA + gb * 1024 + mt * 128 + ks * 64;
        #pragma unroll
        for (int R = 0; R < 2; ++R) {
            int4 whi, wlo;
            whi.x = pack2(acc[R*8+0], acc[R*8+1]);
            whi.y = pack2(acc[R*8+2], acc[R*8+3]);
            whi.z = pack2(acc[R*8+4], acc[R*8+5]);
            whi.w = pack2(acc[R*8+6], acc[R*8+7]);
            wlo.x = pack2(resid(acc[R*8+0]), resid(acc[R*8+1]));
            wlo.y = pack2(resid(acc[R*8+2]), resid(acc[R*8+3]));
            wlo.z = pack2(resid(acc[R*8+4]), resid(acc[R*8+5]));
            wlo.w = pack2(resid(acc[R*8+6]), resid(acc[R*8+7]));
            const int slot = (lgA + R) * 16 + (o & 15);
            wdst[slot]       = whi;          // s = 0 (hi)
            wdst[512 + slot] = wlo;          // s = 1 (lo)
        }
        if (t < 64) {
            const float* b2g = c2b + g * 512;
            float a = 0.f;
            #pragma unroll
            for (int e = 0; e < 8; ++e) a = fmaf(gt[e], b2g[t * 8 + e], a);
            beff[gb * 64 + t] = a;
        }
    } else if (bid < 136) {
        const int g = bid - 128;
        for (int idx = t; idx < 48 * 64; idx += 256) {
            const int j = idx >> 6, o = idx & 63;
            w1r[(size_t)(g * 48 + j) * 64 + o] = c1w[(size_t)g * 3072 + o * 48 + j];
        }
    } else {
        float gates[8];
        const int g = t >> 4, b = t & 15;
        if (t < 128) {
            compute_gates_f(x, wg, g, b, gates);
            #pragma unroll
            for (int e = 0; e < 8; ++e) {
                glds[t][e] = gates[e];
                out[OUT_GATES + (b * 8 + e) * 8 + g] = gates[e];
            }
        }
        __syncthreads();
        if (t < 64) {
            const int gg = t >> 3, e = t & 7;
            float si = 0.f, sl = 0.f;
            for (int bb = 0; bb < 16; ++bb) {
                const float v = glds[gg * 16 + bb][e];
                si += v;
                sl += (v > 0.f) ? 1.f : 0.f;
            }
            impa[t] = si; loda[t] = sl;
        }
        __syncthreads();
        if (t < 8) {
            float m1 = 0.f, m2 = 0.f;
            #pragma unroll
            for (int e = 0; e < 8; ++e) { m1 += impa[t * 8 + e]; m2 += loda[t * 8 + e]; }
            m1 *= 0.125f; m2 *= 0.125f;
            float v1 = 0.f, v2 = 0.f;
            #pragma unroll
            for (int e = 0; e < 8; ++e) {
                const float d1 = impa[t * 8 + e] - m1, d2 = loda[t * 8 + e] - m2;
                v1 += d1 * d1; v2 += d2 * d2;
            }
            v1 *= (1.f / 7.f); v2 *= (1.f / 7.f);
            lossg[t] = v1 / (m1 * m1 + 1e-10f) + v2 / (m2 * m2 + 1e-10f);
        }
        __syncthreads();
        if (t == 0) {
            float tot = 0.f;
            #pragma unroll
            for (int gg = 0; gg < 8; ++gg) tot += lossg[gg];
            out[OUT_LOSS] = 0.01f * tot;
        }
    }
}

// ---------------------------------------------------------------------------
// Main kernel: conv1(VALU) -> tanh -> split-bf16 B-frags in LDS -> MFMA
// (D = Ah*Bh + Ah*Bl + Al*Bh) -> out.  Grid 1024 (XCD-swizzled), 4 waves.
// Phase 1: wave w owns channels 16w..16w+15, lane owns cols (2l, 2l+1).
// Phase 2: wave w owns col-tiles nt = 2w, 2w+1; all 4 o-tiles (mt).
// B k-convention matches prep's A (lane l: k = (l>>4)*8 + e within K-half) --
// any shared k-relabeling cancels in the MFMA dot product.
// C/D layout (m89-verified): col = lane&15, row = (lane>>4)*4 + reg.
// ---------------------------------------------------------------------------
__global__ __launch_bounds__(256, 4) void main_kernel(
    const float* __restrict__ x,    const float* __restrict__ w1r,
    const float* __restrict__ b1,   const int4* __restrict__ weffA,
    const float* __restrict__ beff, float* __restrict__ out)
{
    // h B-fragments: int4 unit index = (s*2+ks)*512 + nt*64 + slot  (32 KB)
    __shared__ int4 hfrag[2048];

    const int bid   = blockIdx.x;
    const int xcd   = bid & 7;
    const int jj    = bid >> 3;
    const int gb    = ((jj & 15) << 3) | xcd;  // same-gb tiles share an XCD
    const int tile  = jj >> 4;                 // 0..7
    const int g     = gb >> 4, b = gb & 15;
    const int t     = threadIdx.x;
    const int lane  = t & 63;
    const int wv    = t >> 6;
    const int obase = __builtin_amdgcn_readfirstlane(wv << 4); // wave-uniform
    const int c0    = lane * 2;
    const int l0    = tile * 128 + c0;
    const int lc    = (l0 <= NLP - 2) ? l0 : (NLP - 2);

    // ---- phase 1: conv1 (16 of 64 channels) + tanh, 2 cols ----
    float a0[16], a1[16];
    const float* b1g = b1 + g * 64 + obase;
    #pragma unroll
    for (int o = 0; o < 16; ++o) { a0[o] = b1g[o]; a1[o] = a0[o]; }

    const float* xb  = x + (size_t)(b * 128 + g * 16) * 1024 + lc;
    const float* wrg = w1r + (size_t)(g * 48) * 64 + obase;

    float2 xaA[8], xcA[8];
    #pragma unroll
    for (int i = 0; i < 8; ++i) {
        xaA[i] = *(const float2*)(xb + i * 1024);
        xcA[i] = *(const float2*)(xb + i * 1024 + 2);
    }
    float2 xaB[8], xcB[8];
    #pragma unroll
    for (int i = 0; i < 8; ++i) {
        xaB[i] = *(const float2*)(xb + (8 + i) * 1024);
        xcB[i] = *(const float2*)(xb + (8 + i) * 1024 + 2);
    }
    #pragma unroll
    for (int i = 0; i < 8; ++i) {
        const float* wr = wrg + i * 192;
        #pragma unroll
        for (int o = 0; o < 16; ++o) {
            const float w0 = wr[o], w1 = wr[64 + o], w2 = wr[128 + o];
            a0[o] = fmaf(w0, xaA[i].x, a0[o]);
            a0[o] = fmaf(w1, xaA[i].y, a0[o]);
            a0[o] = fmaf(w2, xcA[i].x, a0[o]);
            a1[o] = fmaf(w0, xaA[i].y, a1[o]);
            a1[o] = fmaf(w1, xcA[i].x, a1[o]);
            a1[o] = fmaf(w2, xcA[i].y, a1[o]);
        }
    }
    #pragma unroll
    for (int i = 0; i < 8; ++i) {
        const float* wr = wrg + (8 + i) * 192;
        #pragma unroll
        for (int o = 0; o < 16; ++o) {
            const float w0 = wr[o], w1 = wr[64 + o], w2 = wr[128 + o];
            a0[o] = fmaf(w0, xaB[i].x, a0[o]);
            a0[o] = fmaf(w1, xaB[i].y, a0[o]);
            a0[o] = fmaf(w2, xcB[i].x, a0[o]);
            a1[o] = fmaf(w0, xaB[i].y, a1[o]);
            a1[o] = fmaf(w1, xcB[i].x, a1[o]);
            a1[o] = fmaf(w2, xcB[i].y, a1[o]);
        }
    }
    #pragma unroll
    for (int o = 0; o < 16; ++o) { a0[o] = tanh_fast(a0[o]); a1[o] = tanh_fast(a1[o]); }

    // ---- write h as split-bf16 B-fragments into LDS ----
    // channel i = obase + (R*8 + e); ks = obase>>5; lgrp = ((obase>>3)&3) + R
    {
        const int ks1 = obase >> 5;
        const int lg0 = (obase >> 3) & 3;
        #pragma unroll
        for (int cp = 0; cp < 2; ++cp) {
            const int c = c0 + cp;
            const int ub = (c >> 4) * 64 + lg0 * 16 + (c & 15);
            #pragma unroll
            for (int R = 0; R < 2; ++R) {
                float h0, h1, h2, h3, h4, h5, h6, h7;
                if (cp == 0) {
                    h0=a0[R*8+0]; h1=a0[R*8+1]; h2=a0[R*8+2]; h3=a0[R*8+3];
                    h4=a0[R*8+4]; h5=a0[R*8+5]; h6=a0[R*8+6]; h7=a0[R*8+7];
                } else {
                    h0=a1[R*8+0]; h1=a1[R*8+1]; h2=a1[R*8+2]; h3=a1[R*8+3];
                    h4=a1[R*8+4]; h5=a1[R*8+5]; h6=a1[R*8+6]; h7=a1[R*8+7];
                }
                int4 whi, wlo;
                whi.x = pack2(h0, h1); whi.y = pack2(h2, h3);
                whi.z = pack2(h4, h5); whi.w = pack2(h6, h7);
                wlo.x = pack2(resid(h0), resid(h1)); wlo.y = pack2(resid(h2), resid(h3));
                wlo.z = pack2(resid(h4), resid(h5)); wlo.w = pack2(resid(h6), resid(h7));
                hfrag[ks1 * 512 + ub + R * 16]       = whi;  // s = 0
                hfrag[(2 + ks1) * 512 + ub + R * 16] = wlo;  // s = 1
            }
        }
    }

    // bias pre-load (issues before the barrier; drained during barrier wait)
    const int rbase = (lane >> 4) << 2;
    const float* befp = beff + gb * 64 + rbase;
    f32x4 bias0 = *(const f32x4*)(befp);
    f32x4 bias1 = *(const f32x4*)(befp + 16);
    f32x4 bias2 = *(const f32x4*)(befp + 32);
    f32x4 bias3 = *(const f32x4*)(befp + 48);

    __syncthreads();

    // ---- phase 2: MFMA, wave wv owns nt = 2wv, 2wv+1 ----
    const int nt0 = wv * 2;
    f32x4 acc[4][2];
    acc[0][0] = bias0; acc[0][1] = bias0;
    acc[1][0] = bias1; acc[1][1] = bias1;
    acc[2][0] = bias2; acc[2][1] = bias2;
    acc[3][0] = bias3; acc[3][1] = bias3;

    const int4* wAbase = weffA + gb * 1024 + lane;
    #pragma unroll
    for (int ks = 0; ks < 2; ++ks) {
        bf16x8 Bh0 = *(const bf16x8*)&hfrag[ks * 512 + nt0 * 64 + lane];
        bf16x8 Bh1 = *(const bf16x8*)&hfrag[ks * 512 + (nt0 + 1) * 64 + lane];
        bf16x8 Bl0 = *(const bf16x8*)&hfrag[(2 + ks) * 512 + nt0 * 64 + lane];
        bf16x8 Bl1 = *(const bf16x8*)&hfrag[(2 + ks) * 512 + (nt0 + 1) * 64 + lane];
        #pragma unroll
        for (int mt = 0; mt < 4; ++mt) {
            bf16x8 Ah = *(const bf16x8*)(wAbase + mt * 128 + ks * 64);
            bf16x8 Al = *(const bf16x8*)(wAbase + 512 + mt * 128 + ks * 64);
            acc[mt][0] = __builtin_amdgcn_mfma_f32_16x16x32_bf16(Ah, Bh0, acc[mt][0], 0, 0, 0);
            acc[mt][1] = __builtin_amdgcn_mfma_f32_16x16x32_bf16(Ah, Bh1, acc[mt][1], 0, 0, 0);
            acc[mt][0] = __builtin_amdgcn_mfma_f32_16x16x32_bf16(Ah, Bl0, acc[mt][0], 0, 0, 0);
            acc[mt][1] = __builtin_amdgcn_mfma_f32_16x16x32_bf16(Ah, Bl1, acc[mt][1], 0, 0, 0);
            acc[mt][0] = __builtin_amdgcn_mfma_f32_16x16x32_bf16(Al, Bh0, acc[mt][0], 0, 0, 0);
            acc[mt][1] = __builtin_amdgcn_mfma_f32_16x16x32_bf16(Al, Bh1, acc[mt][1], 0, 0, 0);
        }
    }

    // ---- epilogue: D row = mt*16 + rbase + r, col = tile*128 + ntg*16 + (lane&15) ----
    const int colg = tile * 128 + nt0 * 16 + (lane & 15);
    float* outg = out + (size_t)((b * 8 + g) * 64) * NLP;
    #pragma unroll
    for (int mt = 0; mt < 4; ++mt) {
        #pragma unroll
        for (int j = 0; j < 2; ++j) {
            const int cg = colg + j * 16;
            if (cg < NLP) {
                float* orow = outg + (size_t)(mt * 16 + rbase) * NLP + cg;
                orow[0]             = acc[mt][j][0];
                orow[(size_t)NLP]   = acc[mt][j][1];
                orow[(size_t)NLP*2] = acc[mt][j][2];
                orow[(size_t)NLP*3] = acc[mt][j][3];
            }
        }
    }
}

// ---------------------------------------------------------------------------
extern "C" void kernel_launch(void* const* d_in, const int* in_sizes, int n_in,
                              void* d_out, int out_size, void* d_ws, size_t ws_size,
                              hipStream_t stream) {
    const float* x   = (const float*)d_in[0];
    const float* wg  = (const float*)d_in[1];
    const float* c1w = (const float*)d_in[2];
    const float* c1b = (const float*)d_in[3];
    const float* c2w = (const float*)d_in[4];
    const float* c2b = (const float*)d_in[5];
    float* out = (float*)d_out;

    char* ws    = (char*)d_ws;
    int4* weffA = (int4*)ws;                         // 128*1024 int4 = 2 MB
    float* beff = (float*)(ws + (size_t)131072*16);  // 8192 floats
    float* w1r  = beff + 8192;                       // 24576 floats
    // total ws: ~2.13 MB

    prep_kernel<<<137, 256, 0, stream>>>(x, wg, c1w, c2w, c2b, out, weffA, beff, w1r);
    main_kernel<<<1024, 256, 0, stream>>>(x, w1r, c1b, weffA, beff, out);
}

// Round 7
// 110.635 us; speedup vs baseline: 2.8594x; 1.0534x over previous
//
#include <hip/hip_runtime.h>
#include <hip/hip_bf16.h>

// Problem constants
#define NG   8
#define ND   16
#define NL   1024
#define NB   16
#define NE   8
#define NOUT 64
#define NKS  3
#define NK   4
#define NLP  1022   // L - KS + 1

// Output layout (flat concat of reference return tuple)
#define OUT_LOSS  (NB*NG*NOUT*NLP)   // 8372224
#define OUT_GATES (OUT_LOSS + 1)     // 8372225

typedef short bf16x8 __attribute__((ext_vector_type(8)));  // 8 bf16 (4 VGPR)
typedef float f32x4  __attribute__((ext_vector_type(4)));  // MFMA acc

#define MFMA16(A, B, C) __builtin_amdgcn_mfma_f32_16x16x32_bf16((A), (B), (C), 0, 0, 0)

// tanh via exp2: tanh(x) = 1 - 2/(1+2^(2*log2(e)*x)). Correct +-inf limits.
__device__ __forceinline__ float tanh_fast(float x) {
    float e = exp2f(x * 2.885390081777927f);   // 2*log2(e)
    return 1.0f - 2.0f / (e + 1.0f);
}

// --- split-bf16 helpers (truncation split: hi = top16 bits, lo = residual) ---
__device__ __forceinline__ unsigned fbits(float a) { return __builtin_bit_cast(unsigned, a); }
__device__ __forceinline__ float resid(float a) {   // a - bf16_trunc(a), exact
    return a - __builtin_bit_cast(float, fbits(a) & 0xFFFF0000u);
}
// pack bf16_trunc(a) into low 16, bf16_trunc(b) into high 16
__device__ __forceinline__ int pack2(float a, float b) {
    return (int)((fbits(a) >> 16) | (fbits(b) & 0xFFFF0000u));
}

// Gating math for one (g,b): softmax(80x8 matvec) -> top4 -> renorm.
__device__ __forceinline__ void compute_gates_f(
    const float* __restrict__ x, const float* __restrict__ wg,
    int g, int b, float gates[8])
{
    float gi[80];
    const float* xrow = x + (size_t)(b * 128 + g * 16) * 1024 + (1024 - 6);
    #pragma unroll
    for (int d = 0; d < 16; ++d) {
        #pragma unroll
        for (int tt = 0; tt < 5; ++tt) gi[d * 5 + tt] = xrow[d * 1024 + tt];
    }
    float lg[8];
    #pragma unroll
    for (int e = 0; e < 8; ++e) lg[e] = 0.f;
    const float* wgg = wg + g * 640;
    #pragma unroll
    for (int j = 0; j < 80; ++j) {
        const float v = gi[j];
        #pragma unroll
        for (int e = 0; e < 8; ++e) lg[e] = fmaf(v, wgg[j * 8 + e], lg[e]);
    }
    float mx = lg[0];
    #pragma unroll
    for (int e = 1; e < 8; ++e) mx = fmaxf(mx, lg[e]);
    float s = 0.f;
    #pragma unroll
    for (int e = 0; e < 8; ++e) { lg[e] = expf(lg[e] - mx); s += lg[e]; }
    const float invsm = 1.f / s;
    #pragma unroll
    for (int e = 0; e < 8; ++e) lg[e] *= invsm;

    int used = 0;
    float tv[4]; int ti[4];
    #pragma unroll
    for (int k = 0; k < 4; ++k) {
        float bv = -1.f; int be = 0;
        #pragma unroll
        for (int e = 0; e < 8; ++e) {
            if (!((used >> e) & 1) && lg[e] > bv) { bv = lg[e]; be = e; }
        }
        tv[k] = bv; ti[k] = be; used |= (1 << be);
    }
    const float s4 = tv[0] + tv[1] + tv[2] + tv[3];
    const float invs = 1.f / (s4 + 1e-6f);
    #pragma unroll
    for (int e = 0; e < 8; ++e) {
        float v = 0.f;
        #pragma unroll
        for (int k = 0; k < 4; ++k) if (ti[k] == e) v = tv[k] * invs;
        gates[e] = v;
    }
}

// ---------------------------------------------------------------------------
// Prep kernel, 137 blocks x 256 threads:
//   blocks 0..127  : weffA[gb] = split-bf16 A-fragments of (sum_e g_e c2w),
//                    beff[gb]  (gates recomputed locally, scalar path)
//   blocks 128..135: w1fA[g] = split-bf16 A-fragments of conv1 weights,
//                    k-relabeled k = tap*16 + i (pad 48->64 with zeros)
//   block 136      : gates_out + load-balancing loss
//
// Fragment convention (both operands; verified round 6): unit(s,mt,ks) holds
// lane slot = lgrp*16 + (row m | col n), element e <-> k = ks*32 + lgrp*8 + e.
// ---------------------------------------------------------------------------
__global__ __launch_bounds__(256) void prep_kernel(
    const float* __restrict__ x,   const float* __restrict__ wg,
    const float* __restrict__ c1w, const float* __restrict__ c2w,
    const float* __restrict__ c2b,
    float* __restrict__ out, int4* __restrict__ weffA,
    float* __restrict__ beff, int4* __restrict__ w1fA)
{
    const int bid = blockIdx.x;
    const int t   = threadIdx.x;

    __shared__ float glds[128][8];
    __shared__ float impa[64], loda[64];
    __shared__ float lossg[8];

    if (bid < 128) {
        const int gb = bid, g = gb >> 4, b = gb & 15;
        float gt[8];
        compute_gates_f(x, wg, g, b, gt);   // uniform across block

        const int o  = t >> 2;               // 0..63
        const int iq = (t & 3) * 16;         // 0,16,32,48
        const float* w2g = c2w + (size_t)g * 512 * 64 + (size_t)o * 8 * 64 + iq;
        float acc[16];
        #pragma unroll
        for (int q = 0; q < 16; ++q) acc[q] = 0.f;
        #pragma unroll
        for (int e = 0; e < 8; ++e) {
            const float4* src = (const float4*)(w2g + e * 64);
            #pragma unroll
            for (int q = 0; q < 4; ++q) {
                float4 v = src[q];
                acc[q*4+0] = fmaf(gt[e], v.x, acc[q*4+0]);
                acc[q*4+1] = fmaf(gt[e], v.y, acc[q*4+1]);
                acc[q*4+2] = fmaf(gt[e], v.z, acc[q*4+2]);
                acc[q*4+3] = fmaf(gt[e], v.w, acc[q*4+3]);
            }
        }
        // acc[j] = Weff[o][iq + j]; emit split-bf16 A-fragments
        const int mt  = o >> 4;
        const int ks  = iq >> 5;
        const int lgA = (iq & 31) >> 3;      // 0 or 2
        int4* wdst = weffA + gb * 1024 + mt * 128 + ks * 64;
        #pragma unroll
        for (int R = 0; R < 2; ++R) {
            int4 whi, wlo;
            whi.x = pack2(acc[R*8+0], acc[R*8+1]);
            whi.y = pack2(acc[R*8+2], acc[R*8+3]);
            whi.z = pack2(acc[R*8+4], acc[R*8+5]);
            whi.w = pack2(acc[R*8+6], acc[R*8+7]);
            wlo.x = pack2(resid(acc[R*8+0]), resid(acc[R*8+1]));
            wlo.y = pack2(resid(acc[R*8+2]), resid(acc[R*8+3]));
            wlo.z = pack2(resid(acc[R*8+4]), resid(acc[R*8+5]));
            wlo.w = pack2(resid(acc[R*8+6]), resid(acc[R*8+7]));
            const int slot = (lgA + R) * 16 + (o & 15);
            wdst[slot]       = whi;          // s = 0 (hi)
            wdst[512 + slot] = wlo;          // s = 1 (lo)
        }
        if (t < 64) {
            const float* b2g = c2b + g * 512;
            float a = 0.f;
            #pragma unroll
            for (int e = 0; e < 8; ++e) a = fmaf(gt[e], b2g[t * 8 + e], a);
            beff[gb * 64 + t] = a;
        }
    } else if (bid < 136) {
        // ---- conv1 weight split-bf16 A-fragments for g = bid-128 ----
        const int g = bid - 128;
        for (int u = t; u < 1024; u += 256) {
            const int s    = u >> 9;
            const int mt   = (u >> 7) & 3;
            const int ks   = (u >> 6) & 1;
            const int lgrp = (u >> 4) & 3;
            const int m    = u & 15;
            const int o    = mt * 16 + m;
            float v[8];
            #pragma unroll
            for (int e = 0; e < 8; ++e) {
                const int k = ks * 32 + lgrp * 8 + e;     // k = tap*16 + i
                if (k < 48) {
                    const int tap = (k < 32) ? (k >> 4) : 2;
                    const int i   = k & 15;
                    const float w = c1w[((size_t)(g * 64 + o) * 16 + i) * 3 + tap];
                    v[e] = (s == 0) ? w : resid(w);
                } else v[e] = 0.f;
            }
            int4 pk;
            pk.x = pack2(v[0], v[1]); pk.y = pack2(v[2], v[3]);
            pk.z = pack2(v[4], v[5]); pk.w = pack2(v[6], v[7]);
            w1fA[(size_t)g * 1024 + u] = pk;
        }
    } else {
        float gates[8];
        const int g = t >> 4, b = t & 15;
        if (t < 128) {
            compute_gates_f(x, wg, g, b, gates);
            #pragma unroll
            for (int e = 0; e < 8; ++e) {
                glds[t][e] = gates[e];
                out[OUT_GATES + (b * 8 + e) * 8 + g] = gates[e];
            }
        }
        __syncthreads();
        if (t < 64) {
            const int gg = t >> 3, e = t & 7;
            float si = 0.f, sl = 0.f;
            for (int bb = 0; bb < 16; ++bb) {
                const float v = glds[gg * 16 + bb][e];
                si += v;
                sl += (v > 0.f) ? 1.f : 0.f;
            }
            impa[t] = si; loda[t] = sl;
        }
        __syncthreads();
        if (t < 8) {
            float m1 = 0.f, m2 = 0.f;
            #pragma unroll
            for (int e = 0; e < 8; ++e) { m1 += impa[t * 8 + e]; m2 += loda[t * 8 + e]; }
            m1 *= 0.125f; m2 *= 0.125f;
            float v1 = 0.f, v2 = 0.f;
            #pragma unroll
            for (int e = 0; e < 8; ++e) {
                const float d1 = impa[t * 8 + e] - m1, d2 = loda[t * 8 + e] - m2;
                v1 += d1 * d1; v2 += d2 * d2;
            }
            v1 *= (1.f / 7.f); v2 *= (1.f / 7.f);
            lossg[t] = v1 / (m1 * m1 + 1e-10f) + v2 / (m2 * m2 + 1e-10f);
        }
        __syncthreads();
        if (t == 0) {
            float tot = 0.f;
            #pragma unroll
            for (int gg = 0; gg < 8; ++gg) tot += lossg[gg];
            out[OUT_LOSS] = 0.01f * tot;
        }
    }
}

// ---------------------------------------------------------------------------
// Main kernel: BOTH convs on MFMA (split-bf16, D = Ah*Bh + Ah*Bl + Al*Bh).
// Grid 1024 (XCD-swizzled), 4 waves. Wave wv owns col-tiles nt = 2wv, 2wv+1
// for BOTH phases -> the conv1 output it computes is exactly the h its own
// phase 2 consumes (intra-wave LDS reshuffle, no extra barrier).
// LDS 32 KB: hfrag[2048] int4; xtileT (fp32 [136][20], 10.9 KB) aliases the
// front; barrier after B-build retires xtile before hfrag writes land.
// Phase-1 C/D: row o = mt*16 + (lane>>4)*4 + r, col = lane&15 (m89 layout);
// h re-packed to B-frags: lgrp_t = ((mt&1)<<1)+(j>>1), e = (j&1)*4 + r ->
// two ds_write_b64 per (tl,mt).
// ---------------------------------------------------------------------------
__global__ __launch_bounds__(256, 4) void main_kernel(
    const float* __restrict__ x,    const int4* __restrict__ w1fA,
    const float* __restrict__ b1,   const int4* __restrict__ weffA,
    const float* __restrict__ beff, float* __restrict__ out)
{
    __shared__ int4 hfrag[2048];             // 32 KB; per-wave 512-int4 regions
    float* xtileT = (float*)hfrag;           // aliased x stage: [136][20] fp32

    const int bid  = blockIdx.x;
    const int xcd  = bid & 7;
    const int jj   = bid >> 3;
    const int gb   = ((jj & 15) << 3) | xcd; // same-gb tiles share an XCD
    const int tile = jj >> 4;                // 0..7
    const int g    = gb >> 4, b = gb & 15;
    const int t    = threadIdx.x;
    const int lane = t & 63;
    const int wv   = t >> 6;
    const int col  = lane & 15;
    const int j4   = lane >> 4;              // 0..3
    const int l0   = tile * 128;

    // ---- stage x tile transposed: xtileT[c][i], c = 0..129 (clamped) ----
    {
        const int si  = t >> 4;              // channel 0..15
        const int sc0 = t & 15;
        const float* xr = x + (size_t)(b * 128 + g * 16 + si) * 1024;
        #pragma unroll
        for (int kk = 0; kk < 9; ++kk) {
            const int c = sc0 + kk * 16;
            if (c < 130) {
                int gc = l0 + c; if (gc > 1023) gc = 1023;   // tail clamp
                xtileT[c * 20 + si] = xr[gc];
            }
        }
    }
    __syncthreads();

    // ---- build conv1 B-fragments (x) in registers ----
    // k = tap*16 + i: ks=0 -> tap = j4>>1, i0 = (j4&1)*8; ks=1 -> tap=2,
    // i0 = (j4&1)*8, valid only j4 < 2 (k >= 48 zero-padded).
    bf16x8 B1h[2][2], B1l[2][2];
    #pragma unroll
    for (int tl = 0; tl < 2; ++tl) {
        #pragma unroll
        for (int ks = 0; ks < 2; ++ks) {
            const int tap = (ks == 0) ? (j4 >> 1) : 2;
            const int i0  = (j4 & 1) * 8;
            const bool valid = (ks == 0) || (j4 < 2);
            const int c = (wv * 2 + tl) * 16 + col;
            const float* p = &xtileT[(c + tap) * 20 + i0];
            float v[8];
            *(float4*)&v[0] = *(const float4*)p;
            *(float4*)&v[4] = *(const float4*)(p + 4);
            #pragma unroll
            for (int e = 0; e < 8; ++e) if (!valid) v[e] = 0.f;
            int4 bh, bl;
            bh.x = pack2(v[0], v[1]); bh.y = pack2(v[2], v[3]);
            bh.z = pack2(v[4], v[5]); bh.w = pack2(v[6], v[7]);
            bl.x = pack2(resid(v[0]), resid(v[1])); bl.y = pack2(resid(v[2]), resid(v[3]));
            bl.z = pack2(resid(v[4]), resid(v[5])); bl.w = pack2(resid(v[6]), resid(v[7]));
            B1h[tl][ks] = __builtin_bit_cast(bf16x8, bh);
            B1l[tl][ks] = __builtin_bit_cast(bf16x8, bl);
        }
    }
    __syncthreads();   // all waves done with xtileT; hfrag region now writable

    // ---- phase 1: conv1 via MFMA ----
    const int rbase = j4 << 2;
    f32x4 acc1[2][4];                        // [tl][mt]
    #pragma unroll
    for (int mt = 0; mt < 4; ++mt) {
        f32x4 bv = *(const f32x4*)(b1 + g * 64 + mt * 16 + rbase);
        acc1[0][mt] = bv; acc1[1][mt] = bv;
    }
    const int4* w1base = w1fA + g * 1024 + lane;
    #pragma unroll
    for (int mt = 0; mt < 4; ++mt) {
        bf16x8 Ah0 = *(const bf16x8*)(w1base + mt * 128);
        bf16x8 Ah1 = *(const bf16x8*)(w1base + mt * 128 + 64);
        bf16x8 Al0 = *(const bf16x8*)(w1base + 512 + mt * 128);
        bf16x8 Al1 = *(const bf16x8*)(w1base + 512 + mt * 128 + 64);
        #pragma unroll
        for (int tl = 0; tl < 2; ++tl) {
            f32x4 a = acc1[tl][mt];
            a = MFMA16(Ah0, B1h[tl][0], a);
            a = MFMA16(Ah0, B1l[tl][0], a);
            a = MFMA16(Al0, B1h[tl][0], a);
            a = MFMA16(Ah1, B1h[tl][1], a);
            a = MFMA16(Ah1, B1l[tl][1], a);
            a = MFMA16(Al1, B1h[tl][1], a);
            acc1[tl][mt] = a;
        }
    }

    // ---- tanh + repack h into per-wave B-fragment LDS region ----
    {
        char* base = (char*)hfrag;
        const int wb  = wv * 512;
        const int lgt0 = j4 >> 1;
        const int woff = (j4 & 1) * 8;       // byte offset of the word pair
        #pragma unroll
        for (int tl = 0; tl < 2; ++tl) {
            #pragma unroll
            for (int mt = 0; mt < 4; ++mt) {
                const float t0 = tanh_fast(acc1[tl][mt][0]);
                const float t1 = tanh_fast(acc1[tl][mt][1]);
                const float t2 = tanh_fast(acc1[tl][mt][2]);
                const float t3 = tanh_fast(acc1[tl][mt][3]);
                const int kst = mt >> 1;
                const int lgt = ((mt & 1) << 1) + lgt0;
                const int uhi = wb + kst * 128 + tl * 64 + lgt * 16 + col;
                uint2 whi, wlo;
                whi.x = (unsigned)pack2(t0, t1);
                whi.y = (unsigned)pack2(t2, t3);
                wlo.x = (unsigned)pack2(resid(t0), resid(t1));
                wlo.y = (unsigned)pack2(resid(t2), resid(t3));
                *(uint2*)(base + uhi * 16 + woff)         = whi;   // s=0
                *(uint2*)(base + (uhi + 256) * 16 + woff) = wlo;   // s=1
            }
        }
    }

    // ---- phase 2: gate-folded 64x64 via MFMA (intra-wave h read-back) ----
    f32x4 acc2[4][2];
    const float* befp = beff + gb * 64 + rbase;
    #pragma unroll
    for (int mt = 0; mt < 4; ++mt) {
        f32x4 bv = *(const f32x4*)(befp + mt * 16);
        acc2[mt][0] = bv; acc2[mt][1] = bv;
    }
    const int4* wAbase = weffA + gb * 1024 + lane;
    #pragma unroll
    for (int ks = 0; ks < 2; ++ks) {
        const int wb = wv * 512;
        bf16x8 Bh0 = *(const bf16x8*)&hfrag[wb + ks * 128 + lane];
        bf16x8 Bh1 = *(const bf16x8*)&hfrag[wb + ks * 128 + 64 + lane];
        bf16x8 Bl0 = *(const bf16x8*)&hfrag[wb + (2 + ks) * 128 + lane];
        bf16x8 Bl1 = *(const bf16x8*)&hfrag[wb + (2 + ks) * 128 + 64 + lane];
        #pragma unroll
        for (int mt = 0; mt < 4; ++mt) {
            bf16x8 Ah = *(const bf16x8*)(wAbase + mt * 128 + ks * 64);
            bf16x8 Al = *(const bf16x8*)(wAbase + 512 + mt * 128 + ks * 64);
            acc2[mt][0] = MFMA16(Ah, Bh0, acc2[mt][0]);
            acc2[mt][1] = MFMA16(Ah, Bh1, acc2[mt][1]);
            acc2[mt][0] = MFMA16(Ah, Bl0, acc2[mt][0]);
            acc2[mt][1] = MFMA16(Ah, Bl1, acc2[mt][1]);
            acc2[mt][0] = MFMA16(Al, Bh0, acc2[mt][0]);
            acc2[mt][1] = MFMA16(Al, Bh1, acc2[mt][1]);
        }
    }

    // ---- epilogue: row = mt*16 + rbase + r, col = l0 + (2wv+tl)*16 + col ----
    const int colg = l0 + wv * 32 + col;
    float* outg = out + (size_t)((b * 8 + g) * 64) * NLP;
    #pragma unroll
    for (int mt = 0; mt < 4; ++mt) {
        #pragma unroll
        for (int tl = 0; tl < 2; ++tl) {
            const int cg = colg + tl * 16;
            if (cg < NLP) {
                float* orow = outg + (size_t)(mt * 16 + rbase) * NLP + cg;
                orow[0]             = acc2[mt][tl][0];
                orow[(size_t)NLP]   = acc2[mt][tl][1];
                orow[(size_t)NLP*2] = acc2[mt][tl][2];
                orow[(size_t)NLP*3] = acc2[mt][tl][3];
            }
        }
    }
}

// ---------------------------------------------------------------------------
extern "C" void kernel_launch(void* const* d_in, const int* in_sizes, int n_in,
                              void* d_out, int out_size, void* d_ws, size_t ws_size,
                              hipStream_t stream) {
    const float* x   = (const float*)d_in[0];
    const float* wg  = (const float*)d_in[1];
    const float* c1w = (const float*)d_in[2];
    const float* c1b = (const float*)d_in[3];
    const float* c2w = (const float*)d_in[4];
    const float* c2b = (const float*)d_in[5];
    float* out = (float*)d_out;

    char* ws    = (char*)d_ws;
    int4* weffA = (int4*)ws;                     // 128*1024 int4 = 2 MB
    int4* w1fA  = weffA + 131072;                // 8*1024 int4   = 128 KB
    float* beff = (float*)(w1fA + 8192);         // 8192 floats   = 32 KB
    // total ws: ~2.16 MB

    prep_kernel<<<137, 256, 0, stream>>>(x, wg, c1w, c2w, c2b, out, weffA, beff, w1fA);
    main_kernel<<<1024, 256, 0, stream>>>(x, w1fA, c1b, weffA, beff, out);
}